// Round 4
// baseline (198.495 us; speedup 1.0000x reference)
//
#include <hip/hip_runtime.h>
#include <math.h>

#define BATCH 64
#define TLEN  256
#define NCLS  2500
#define BLANK (NCLS - 1)
#define EPSF  1e-7f
#define NF4   (NCLS / 4)                 // 625 float4 per row
#define FULL_IT 9                        // 9*64 = 576; tail = 49
#define TAIL_LANES (NF4 - FULL_IT * 64)  // 49
#define BLOCKS_PER_BATCH (TLEN / 4)      // 64

// Fused: phase 1 = one wave per (b,t) row argmax (4 rows/block);
// phase 2 = the last-finishing block of each batch decodes that batch.
// Cross-XCD visibility: release = __threadfence (L2 wb) before atomicAdd,
// acquire = __threadfence (L2 inv) after observing count==63.
__global__ __launch_bounds__(256) void ctc_fused_kernel(
    const float* __restrict__ in, int* __restrict__ best, float* __restrict__ maxlp,
    unsigned* __restrict__ cnt, float* __restrict__ dec, float* __restrict__ score) {
  const int wid  = threadIdx.x >> 6;
  const int lane = threadIdx.x & 63;
  const int row  = (blockIdx.x << 2) + wid;
  const int b    = blockIdx.x >> 6;    // 64 consecutive blocks per batch
  const float4* __restrict__ p4 = (const float4*)(in + (size_t)row * NCLS) + lane;

  // ---- phase 1: row argmax ----
  float4 v[FULL_IT + 1];
  #pragma unroll
  for (int it = 0; it < FULL_IT; ++it) v[it] = p4[it << 6];
  const bool tail = lane < TAIL_LANES;
  if (tail) v[FULL_IT] = p4[FULL_IT << 6];

  float vmax = -1.0f;   // probs >= 0
  int   vidx = 0;
  #pragma unroll
  for (int it = 0; it < FULL_IT; ++it) {       // in-lane idx increasing -> '>' keeps first
    const int base = (it << 8) + (lane << 2);
    if (v[it].x > vmax) { vmax = v[it].x; vidx = base;     }
    if (v[it].y > vmax) { vmax = v[it].y; vidx = base + 1; }
    if (v[it].z > vmax) { vmax = v[it].z; vidx = base + 2; }
    if (v[it].w > vmax) { vmax = v[it].w; vidx = base + 3; }
  }
  if (tail) {
    const int base = (FULL_IT << 8) + (lane << 2);
    if (v[FULL_IT].x > vmax) { vmax = v[FULL_IT].x; vidx = base;     }
    if (v[FULL_IT].y > vmax) { vmax = v[FULL_IT].y; vidx = base + 1; }
    if (v[FULL_IT].z > vmax) { vmax = v[FULL_IT].z; vidx = base + 2; }
    if (v[FULL_IT].w > vmax) { vmax = v[FULL_IT].w; vidx = base + 3; }
  }
  for (int off = 32; off > 0; off >>= 1) {     // larger val wins; tie -> smaller idx
    float ov = __shfl_down(vmax, off);
    int   oi = __shfl_down(vidx, off);
    if (ov > vmax || (ov == vmax && oi < vidx)) { vmax = ov; vidx = oi; }
  }
  if (lane == 0) {
    best[row]  = vidx;
    maxlp[row] = logf(vmax + EPSF);
  }

  // ---- arrival: last block of this batch decodes it ----
  __syncthreads();                         // drains this block's stores (vmcnt 0)
  __shared__ int s_last;
  if (threadIdx.x == 0) {
    __threadfence();                       // release: write back XCD L2
    unsigned old = atomicAdd(&cnt[b], 1u);
    s_last = (old == (unsigned)(BLOCKS_PER_BATCH - 1));
  }
  __syncthreads();
  if (!s_last) return;
  __threadfence();                         // acquire: invalidate stale L2 lines

  // ---- phase 2: decode batch b (256 threads, one per frame) ----
  const int t = threadIdx.x;
  const int my   = best[b * TLEN + t];
  const int prev = (t == 0) ? -1 : best[b * TLEN + t - 1];
  const int keep = (my != BLANK && my != prev) ? 1 : 0;

  int x = keep;                            // inclusive wave scan
  #pragma unroll
  for (int off = 1; off < 64; off <<= 1) {
    int y = __shfl_up(x, off);
    if (lane >= off) x += y;
  }
  __shared__ int   s_wsum[4];
  __shared__ float s_fsum[4];
  if (lane == 63) s_wsum[wid] = x;

  float s = maxlp[b * TLEN + t];           // wave sum of max log-probs
  #pragma unroll
  for (int off = 32; off > 0; off >>= 1) s += __shfl_down(s, off);
  if (lane == 0) s_fsum[wid] = s;
  __syncthreads();

  int offset = 0;
  #pragma unroll
  for (int w = 0; w < 4; ++w) offset += (w < wid) ? s_wsum[w] : 0;
  const int pos = offset + x - 1;

  dec[b * TLEN + t] = -1.0f;
  __syncthreads();
  if (keep) dec[b * TLEN + pos] = (float)my;

  if (t == 0) score[b] = -(s_fsum[0] + s_fsum[1] + s_fsum[2] + s_fsum[3]);
}

extern "C" void kernel_launch(void* const* d_in, const int* in_sizes, int n_in,
                              void* d_out, int out_size, void* d_ws, size_t ws_size,
                              hipStream_t stream) {
  const float* in = (const float*)d_in[0];
  float* out = (float*)d_out;              // [B*T] decoded (as f32), then [B] scores
  int*      best  = (int*)d_ws;                                     // 64 KiB
  float*    maxlp = (float*)((char*)d_ws + (size_t)BATCH * TLEN * 4);  // 64 KiB
  unsigned* cnt   = (unsigned*)((char*)d_ws + (size_t)BATCH * TLEN * 8); // 256 B

  hipMemsetAsync(cnt, 0, BATCH * sizeof(unsigned), stream);
  ctc_fused_kernel<<<(BATCH * TLEN) / 4, 256, 0, stream>>>(
      in, best, maxlp, cnt, out, out + BATCH * TLEN);
}

// Round 5
// 55.008 us; speedup vs baseline: 3.6085x; 3.6085x over previous
//
#include <hip/hip_runtime.h>
#include <math.h>

#define BATCH 64
#define TLEN  256
#define NCLS  2500
#define BLANK (NCLS - 1)
#define EPSF  1e-7f
#define NF4   (NCLS / 4)                 // 625 float4 per row
#define FULL_IT 9                        // 9*64 = 576; tail = 49
#define TAIL_LANES (NF4 - FULL_IT * 64)  // 49
#define BLOCKS_PER_BATCH (TLEN / 4)      // 64

// Fused CTC decode. Phase 1: one wave per (b,t) row argmax (4 rows/block).
// Publish results via RETURNING atomicExch (performs at the device coherence
// point; consuming the return forces vmcnt wait -> atomic completed before the
// arrival counter below). NO __threadfence — round-4 showed device fences emit
// L2 writeback/invalidate ops that serialized the chip (313us vs 32us).
// Phase 2: the 64th-arriving block of each batch decodes it, reading
// best/maxlp via atomic reads (atomicAdd(p,0)) which bypass stale per-XCD L2.
__global__ __launch_bounds__(256) void ctc_fused_kernel(
    const float* __restrict__ in, int* best, float* maxlp,
    unsigned* cnt, float* __restrict__ dec, float* __restrict__ score) {
  const int wid  = threadIdx.x >> 6;
  const int lane = threadIdx.x & 63;
  const int row  = (blockIdx.x << 2) + wid;
  const int b    = blockIdx.x >> 6;    // 64 consecutive blocks per batch
  const float4* __restrict__ p4 = (const float4*)(in + (size_t)row * NCLS) + lane;

  // ---- phase 1: row argmax (identical to round-3 known-good) ----
  float4 v[FULL_IT + 1];
  #pragma unroll
  for (int it = 0; it < FULL_IT; ++it) v[it] = p4[it << 6];
  const bool tail = lane < TAIL_LANES;
  if (tail) v[FULL_IT] = p4[FULL_IT << 6];

  float vmax = -1.0f;   // probs >= 0
  int   vidx = 0;
  #pragma unroll
  for (int it = 0; it < FULL_IT; ++it) {       // in-lane idx increasing -> '>' keeps first
    const int base = (it << 8) + (lane << 2);
    if (v[it].x > vmax) { vmax = v[it].x; vidx = base;     }
    if (v[it].y > vmax) { vmax = v[it].y; vidx = base + 1; }
    if (v[it].z > vmax) { vmax = v[it].z; vidx = base + 2; }
    if (v[it].w > vmax) { vmax = v[it].w; vidx = base + 3; }
  }
  if (tail) {
    const int base = (FULL_IT << 8) + (lane << 2);
    if (v[FULL_IT].x > vmax) { vmax = v[FULL_IT].x; vidx = base;     }
    if (v[FULL_IT].y > vmax) { vmax = v[FULL_IT].y; vidx = base + 1; }
    if (v[FULL_IT].z > vmax) { vmax = v[FULL_IT].z; vidx = base + 2; }
    if (v[FULL_IT].w > vmax) { vmax = v[FULL_IT].w; vidx = base + 3; }
  }
  for (int off = 32; off > 0; off >>= 1) {     // larger val wins; tie -> smaller idx
    float ov = __shfl_down(vmax, off);
    int   oi = __shfl_down(vidx, off);
    if (ov > vmax || (ov == vmax && oi < vidx)) { vmax = ov; vidx = oi; }
  }

  // ---- publish via returning atomics (device coherence point) ----
  if (lane == 0) {
    int   oi = atomicExch(&best[row], vidx);
    float of = atomicExch(&maxlp[row], logf(vmax + EPSF));
    asm volatile("" :: "v"(oi), "v"(of));  // use returns -> s_waitcnt -> atomics performed
  }
  __syncthreads();                         // all 4 waves published

  __shared__ int s_last;
  if (threadIdx.x == 0) {
    unsigned old = atomicAdd(&cnt[b], 1u);
    s_last = (old == (unsigned)(BLOCKS_PER_BATCH - 1));
  }
  __syncthreads();
  if (!s_last) return;

  // ---- phase 2: decode batch b (this block only) ----
  const int t = threadIdx.x;
  __shared__ int   s_best[TLEN];
  __shared__ int   s_wsum[4];
  __shared__ float s_fsum[4];

  s_best[t] = atomicAdd(&best[b * TLEN + t], 0);        // coherent read
  float mlp = atomicAdd(&maxlp[b * TLEN + t], 0.0f);    // coherent read

  #pragma unroll
  for (int off = 32; off > 0; off >>= 1) mlp += __shfl_down(mlp, off);
  if (lane == 0) s_fsum[wid] = mlp;
  __syncthreads();                         // s_best + s_fsum ready

  const int my   = s_best[t];
  const int prev = (t == 0) ? -1 : s_best[t - 1];
  const int keep = (my != BLANK && my != prev) ? 1 : 0;

  int x = keep;                            // inclusive wave scan
  #pragma unroll
  for (int off = 1; off < 64; off <<= 1) {
    int y = __shfl_up(x, off);
    if (lane >= off) x += y;
  }
  if (lane == 63) s_wsum[wid] = x;
  __syncthreads();

  int offset = 0;
  #pragma unroll
  for (int w = 0; w < 4; ++w) offset += (w < wid) ? s_wsum[w] : 0;
  const int pos = offset + x - 1;

  dec[b * TLEN + t] = -1.0f;
  __syncthreads();
  if (keep) dec[b * TLEN + pos] = (float)my;

  if (t == 0) score[b] = -(s_fsum[0] + s_fsum[1] + s_fsum[2] + s_fsum[3]);
}

extern "C" void kernel_launch(void* const* d_in, const int* in_sizes, int n_in,
                              void* d_out, int out_size, void* d_ws, size_t ws_size,
                              hipStream_t stream) {
  const float* in = (const float*)d_in[0];
  float* out = (float*)d_out;              // [B*T] decoded (as f32), then [B] scores
  int*      best  = (int*)d_ws;                                        // 64 KiB
  float*    maxlp = (float*)((char*)d_ws + (size_t)BATCH * TLEN * 4);  // 64 KiB
  unsigned* cnt   = (unsigned*)((char*)d_ws + (size_t)BATCH * TLEN * 8); // 256 B

  hipMemsetAsync(cnt, 0, BATCH * sizeof(unsigned), stream);
  ctc_fused_kernel<<<(BATCH * TLEN) / 4, 256, 0, stream>>>(
      in, best, maxlp, cnt, out, out + BATCH * TLEN);
}

// Round 6
// 29.801 us; speedup vs baseline: 6.6607x; 1.8459x over previous
//
#include <hip/hip_runtime.h>
#include <math.h>

#define BATCH 64
#define TLEN  256
#define NCLS  2500
#define BLANK (NCLS - 1)
#define EPSF  1e-7f
#define NF4   (NCLS / 4)                 // 625 float4 per row
#define FULL_IT 9                        // 9*64 = 576; tail = 49
#define TAIL_LANES (NF4 - FULL_IT * 64)  // 49

typedef float f32x4 __attribute__((ext_vector_type(4)));

// Kernel 1: one WAVE per (b,t) row. 4 waves/block, grid = B*T/4.
// Streaming 164 MB read with zero reuse -> nontemporal loads (nt, bypass L2
// allocation). Results packed into one int2 store per row.
__global__ __launch_bounds__(256) void ctc_rowmax_kernel(
    const float* __restrict__ in, int2* __restrict__ bml) {
  const int wid  = threadIdx.x >> 6;
  const int lane = threadIdx.x & 63;
  const int row  = (blockIdx.x << 2) + wid;
  const f32x4* __restrict__ p4 = (const f32x4*)(in + (size_t)row * NCLS) + lane;

  f32x4 v[FULL_IT + 1];
  #pragma unroll
  for (int it = 0; it < FULL_IT; ++it) v[it] = __builtin_nontemporal_load(p4 + (it << 6));
  const bool tail = lane < TAIL_LANES;
  if (tail) v[FULL_IT] = __builtin_nontemporal_load(p4 + (FULL_IT << 6));

  float vmax = -1.0f;   // probs >= 0
  int   vidx = 0;
  #pragma unroll
  for (int it = 0; it < FULL_IT; ++it) {       // in-lane idx increasing -> '>' keeps first
    const int base = (it << 8) + (lane << 2);
    if (v[it].x > vmax) { vmax = v[it].x; vidx = base;     }
    if (v[it].y > vmax) { vmax = v[it].y; vidx = base + 1; }
    if (v[it].z > vmax) { vmax = v[it].z; vidx = base + 2; }
    if (v[it].w > vmax) { vmax = v[it].w; vidx = base + 3; }
  }
  if (tail) {
    const int base = (FULL_IT << 8) + (lane << 2);
    if (v[FULL_IT].x > vmax) { vmax = v[FULL_IT].x; vidx = base;     }
    if (v[FULL_IT].y > vmax) { vmax = v[FULL_IT].y; vidx = base + 1; }
    if (v[FULL_IT].z > vmax) { vmax = v[FULL_IT].z; vidx = base + 2; }
    if (v[FULL_IT].w > vmax) { vmax = v[FULL_IT].w; vidx = base + 3; }
  }

  for (int off = 32; off > 0; off >>= 1) {     // larger val wins; tie -> smaller idx
    float ov = __shfl_down(vmax, off);
    int   oi = __shfl_down(vidx, off);
    if (ov > vmax || (ov == vmax && oi < vidx)) { vmax = ov; vidx = oi; }
  }
  if (lane == 0) bml[row] = make_int2(vidx, __float_as_int(logf(vmax + EPSF)));
}

// Kernel 2: per-batch merge-repeats/remove-blank + score, f32 outputs.
// Grid = B blocks, 256 threads. prev via __shfl_up (wave-boundary lanes load).
__global__ __launch_bounds__(256) void ctc_decode_kernel(
    const int2* __restrict__ bml, float* __restrict__ dec, float* __restrict__ score) {
  const int b = blockIdx.x, t = threadIdx.x;
  const int lane = t & 63, wid = t >> 6;

  const int2 bm = bml[b * TLEN + t];
  const int   my  = bm.x;
  const float mlp = __int_as_float(bm.y);

  const int prevw = __shfl_up(my, 1);
  const int prev  = (t == 0) ? -1 : (lane == 0 ? bml[b * TLEN + t - 1].x : prevw);
  const int keep  = (my != BLANK && my != prev) ? 1 : 0;

  // inclusive wave scan of keep
  int x = keep;
  #pragma unroll
  for (int off = 1; off < 64; off <<= 1) {
    int y = __shfl_up(x, off);
    if (lane >= off) x += y;
  }
  __shared__ int   s_wsum[4];
  __shared__ float s_fsum[4];
  if (lane == 63) s_wsum[wid] = x;

  float s = mlp;                           // wave sum of max log-probs
  #pragma unroll
  for (int off = 32; off > 0; off >>= 1) s += __shfl_down(s, off);
  if (lane == 0) s_fsum[wid] = s;
  __syncthreads();

  int offset = 0;
  #pragma unroll
  for (int w = 0; w < 4; ++w) offset += (w < wid) ? s_wsum[w] : 0;
  const int pos = offset + x - 1;

  dec[b * TLEN + t] = -1.0f;
  __syncthreads();
  if (keep) dec[b * TLEN + pos] = (float)my;

  if (t == 0) score[b] = -(s_fsum[0] + s_fsum[1] + s_fsum[2] + s_fsum[3]);
}

extern "C" void kernel_launch(void* const* d_in, const int* in_sizes, int n_in,
                              void* d_out, int out_size, void* d_ws, size_t ws_size,
                              hipStream_t stream) {
  const float* in = (const float*)d_in[0];
  float* out = (float*)d_out;              // [B*T] decoded (as f32), then [B] scores
  int2* bml = (int2*)d_ws;                 // B*T int2 (128 KiB)

  ctc_rowmax_kernel<<<(BATCH * TLEN) / 4, 256, 0, stream>>>(in, bml);
  ctc_decode_kernel<<<BATCH, 256, 0, stream>>>(bml, out, out + BATCH * TLEN);
}